// Round 14
// baseline (575.439 us; speedup 1.0000x reference)
//
#include <hip/hip_runtime.h>

// Sggnn_23218593202512 — round 14: launch-quantization attack. t (512 fat
// blocks) and affinity (544 light blocks) are data-independent; merged into
// ONE launch (t first, aff backfills t's 2nd round + absorbs aff's 32-block
// straggler). Bodies are the verified R13 gemm256 (plain path) and R12
// gemm_aff, unchanged, behind a block-ID branch. h/uT/feat identical to R13.

typedef __bf16 bf16;
typedef __attribute__((ext_vector_type(8))) __bf16 bf16x8;
typedef __attribute__((ext_vector_type(4))) float f32x4;

#define EPSV 1e-5f

__device__ __forceinline__ void async_load16(const bf16* g, bf16* l) {
    __builtin_amdgcn_global_load_lds(
        (const __attribute__((address_space(1))) void*)g,
        (__attribute__((address_space(3))) void*)l, 16, 0, 0);
}

__global__ __launch_bounds__(256) void prep_kernel(
    const float* __restrict__ g, const float* __restrict__ b,
    const float* __restrict__ m, const float* __restrict__ v,
    const float* __restrict__ bias, float* __restrict__ scale,
    float* __restrict__ offset, int n)
{
    int i = blockIdx.x * 256 + threadIdx.x;
    if (i >= n) return;
    float s = g[i] / sqrtf(v[i] + EPSV);
    float o = b[i] - m[i] * s;
    if (bias) o += bias[i] * s;
    scale[i] = s;
    offset[i] = o;
}

__global__ __launch_bounds__(256) void wtrans_kernel(
    const float* __restrict__ in, bf16* __restrict__ out, int K, int N)
{
    int k = blockIdx.x * 256 + threadIdx.x;
    int n = blockIdx.y;
    out[(size_t)n * K + k] = (bf16)in[(size_t)k * N + n];
}

// wT[g2*256+g1] = bf16(w[g1][g2] + scl_b); g-tiles ta<=tb computed, mirrored.
__global__ __launch_bounds__(256) void wconv_kernel(
    const float* __restrict__ w_acc, const float* __restrict__ sclb,
    bf16* __restrict__ wT)
{
    int tid = blockIdx.x * 256 + threadIdx.x;
    int g2 = tid >> 8, g1 = tid & 255;
    int idx = ((g1 >> 4) <= (g2 >> 4)) ? (g1 * 256 + g2) : (g2 * 256 + g1);
    wT[tid] = (bf16)(w_acc[idx] + sclb[0]);
}

__global__ __launch_bounds__(256) void finout_kernel(
    const float* __restrict__ acc, const float* __restrict__ clsb,
    float* __restrict__ out)
{
    int i = blockIdx.x * 256 + threadIdx.x;
    out[i] = acc[i] + clsb[0];
}

// ---------- device body: gemm256 plain (non-pair, non-batch, store) --------
// 256x256 block, 8 waves (2 row x 4 col), wave 128x64 (acc[8][4]), BK=64.
__device__ __forceinline__ void dev_gemm256_plain(
    bf16* As, bf16* Bs,
    const bf16* __restrict__ A, const bf16* __restrict__ BT,
    bf16* __restrict__ C, int K, int N, int row0, int col0,
    const float* __restrict__ scale, const float* __restrict__ offset,
    int lrelu)
{
    const int tid  = threadIdx.x;
    const int lane = tid & 63;
    const int wave = tid >> 6;
    const int wrow = wave >> 2, wcol = wave & 3;
    const int q = lane >> 4, l16 = lane & 15;

    f32x4 acc[8][4];
#pragma unroll
    for (int mi = 0; mi < 8; ++mi)
#pragma unroll
        for (int ni = 0; ni < 4; ++ni)
#pragma unroll
            for (int e = 0; e < 4; ++e) acc[mi][ni][e] = 0.f;

    for (int kk = 0; kk < K; kk += 64) {
#pragma unroll
        for (int t = 0; t < 4; ++t) {
            int idx = t * 512 + tid;
            int r = idx >> 3, sch = idx & 7;
            int gch = sch ^ (r & 7);
            async_load16(A + (size_t)(row0 + r) * K + kk + gch * 8,
                         &As[idx * 8]);
        }
#pragma unroll
        for (int t = 0; t < 4; ++t) {
            int idx = t * 512 + tid;
            int r = idx >> 3, sch = idx & 7;
            int gch = sch ^ (r & 7);
            async_load16(BT + (size_t)(col0 + r) * K + kk + gch * 8,
                         &Bs[idx * 8]);
        }
        __syncthreads();
#pragma unroll
        for (int s = 0; s < 2; ++s) {
            bf16x8 af[8], bfr[4];
#pragma unroll
            for (int mi = 0; mi < 8; ++mi) {
                int r = wrow * 128 + mi * 16 + l16;
                af[mi] = *(const bf16x8*)&As[r * 64 + (((s * 4 + q) ^ (r & 7)) * 8)];
            }
#pragma unroll
            for (int ni = 0; ni < 4; ++ni) {
                int rc = wcol * 64 + ni * 16 + l16;
                bfr[ni] = *(const bf16x8*)&Bs[rc * 64 + (((s * 4 + q) ^ (rc & 7)) * 8)];
            }
#pragma unroll
            for (int mi = 0; mi < 8; ++mi)
#pragma unroll
                for (int ni = 0; ni < 4; ++ni)
                    acc[mi][ni] = __builtin_amdgcn_mfma_f32_16x16x32_bf16(
                        af[mi], bfr[ni], acc[mi][ni], 0, 0, 0);
        }
        __syncthreads();
    }

#pragma unroll
    for (int mi = 0; mi < 8; ++mi)
#pragma unroll
        for (int ni = 0; ni < 4; ++ni)
#pragma unroll
            for (int i = 0; i < 4; ++i) {
                int r = row0 + wrow * 128 + mi * 16 + q * 4 + i;
                int cc = col0 + wcol * 64 + ni * 16 + l16;
                float val = acc[mi][ni][i];
                if (scale) val = val * scale[cc] + offset[cc];
                if (lrelu) val = val > 0.f ? val : 0.1f * val;
                C[(size_t)r * N + cc] = (bf16)val;
            }
}

// ---------- device body: symmetric affinity (R12-verified), 256x128 --------
__device__ __forceinline__ void dev_aff(
    bf16* As, bf16* Bs,
    const float* __restrict__ pairX,
    const float* __restrict__ ps, const float* __restrict__ po,
    const bf16* __restrict__ BT, int K, int col0, int triIdx,
    const float* __restrict__ scale, const float* __restrict__ offset,
    const float* __restrict__ sclW, float* __restrict__ w_acc)
{
    const int tid  = threadIdx.x;
    const int lane = tid & 63;
    const int wave = tid >> 6;
    const int wrow = wave >> 1, wcol = wave & 1;
    const int q = lane >> 4, l16 = lane & 15;

    int ta = 0, rem = triIdx;
    while (rem >= 16 - ta) { rem -= 16 - ta; ++ta; }
    const int tb = ta + rem;

    f32x4 acc[4][4];
#pragma unroll
    for (int mi = 0; mi < 4; ++mi)
#pragma unroll
        for (int ni = 0; ni < 4; ++ni)
#pragma unroll
            for (int e = 0; e < 4; ++e) acc[mi][ni][e] = 0.f;

    for (int kk = 0; kk < K; kk += 64) {
#pragma unroll
        for (int t = 0; t < 4; ++t) {
            int c = tid + t * 512;          // 2048 tasks: r=c>>3, ch=c&7
            int r = c >> 3, ch = c & 7;
            int g1 = ta * 16 + (r >> 4), g2 = tb * 16 + (r & 15);
            const float* xp = pairX + (size_t)g1 * K + kk + ch * 8;
            const float* yp = pairX + (size_t)g2 * K + kk + ch * 8;
            f32x4 x0 = *(const f32x4*)xp, x1 = *(const f32x4*)(xp + 4);
            f32x4 y0 = *(const f32x4*)yp, y1 = *(const f32x4*)(yp + 4);
            f32x4 sa = *(const f32x4*)(ps + kk + ch * 8);
            f32x4 sb = *(const f32x4*)(ps + kk + ch * 8 + 4);
            f32x4 oa = *(const f32x4*)(po + kk + ch * 8);
            f32x4 ob = *(const f32x4*)(po + kk + ch * 8 + 4);
            bf16x8 dv;
#pragma unroll
            for (int j = 0; j < 4; ++j) {
                float d0 = x0[j] - y0[j];
                float d1 = x1[j] - y1[j];
                dv[j]     = (bf16)(d0 * d0 * sa[j] + oa[j]);
                dv[j + 4] = (bf16)(d1 * d1 * sb[j] + ob[j]);
            }
            *(bf16x8*)&As[r * 64 + ((ch ^ (r & 7)) * 8)] = dv;
        }
#pragma unroll
        for (int t = 0; t < 2; ++t) {
            int idx = t * 512 + tid;        // 1024 chunks
            int r = idx >> 3, sch = idx & 7;
            int gch = sch ^ (r & 7);
            async_load16(BT + (size_t)(col0 + r) * K + kk + gch * 8,
                         &Bs[idx * 8]);
        }
        __syncthreads();

#pragma unroll
        for (int s = 0; s < 2; ++s) {
            bf16x8 af[4], bfr[4];
#pragma unroll
            for (int mi = 0; mi < 4; ++mi) {
                int r = wrow * 64 + mi * 16 + l16;
                af[mi] = *(const bf16x8*)&As[r * 64 + (((s * 4 + q) ^ (r & 7)) * 8)];
            }
#pragma unroll
            for (int ni = 0; ni < 4; ++ni) {
                int rc = wcol * 64 + ni * 16 + l16;
                bfr[ni] = *(const bf16x8*)&Bs[rc * 64 + (((s * 4 + q) ^ (rc & 7)) * 8)];
            }
#pragma unroll
            for (int mi = 0; mi < 4; ++mi)
#pragma unroll
                for (int ni = 0; ni < 4; ++ni)
                    acc[mi][ni] = __builtin_amdgcn_mfma_f32_16x16x32_bf16(
                        af[mi], bfr[ni], acc[mi][ni], 0, 0, 0);
        }
        __syncthreads();
    }

#pragma unroll
    for (int mi = 0; mi < 4; ++mi)
#pragma unroll
        for (int i = 0; i < 4; ++i) {
            float rs = 0.f;
#pragma unroll
            for (int ni = 0; ni < 4; ++ni) {
                int cc = col0 + wcol * 64 + ni * 16 + l16;
                float val = acc[mi][ni][i] * scale[cc] + offset[cc];
                val = val > 0.f ? val : 0.1f * val;
                rs += val * sclW[cc];
            }
            rs += __shfl_xor(rs, 1, 64);
            rs += __shfl_xor(rs, 2, 64);
            rs += __shfl_xor(rs, 4, 64);
            rs += __shfl_xor(rs, 8, 64);
            if (l16 == 0) {
                int r = wrow * 64 + mi * 16 + q * 4 + i;
                int g1 = ta * 16 + (r >> 4), g2 = tb * 16 + (r & 15);
                atomicAdd(w_acc + g1 * 256 + g2, rs);
            }
        }
}

// ---------- merged t + affinity launch -------------------------------------
// blocks [0, tBlocks): t = lrelu(rf2(h @ W2)) — fat gemm256 blocks.
// blocks [tBlocks, tBlocks+544): symmetric affinity — lighter blocks backfill.
__global__ __launch_bounds__(512) void gemm_taff(
    const bf16* __restrict__ hbuf, const bf16* __restrict__ W2T,
    bf16* __restrict__ tbuf,
    const float* __restrict__ s2, const float* __restrict__ o2,
    const float* __restrict__ f_g,
    const float* __restrict__ ps0, const float* __restrict__ po0,
    const bf16* __restrict__ sfcT,
    const float* __restrict__ s3, const float* __restrict__ o3,
    const float* __restrict__ sclW, float* __restrict__ w_acc,
    int tBlocks)
{
    __shared__ bf16 As[256 * 64];   // 32 KiB
    __shared__ bf16 Bs[256 * 64];   // 32 KiB (aff uses first 16 KiB)
    int b = blockIdx.x;
    if (b < tBlocks) {
        dev_gemm256_plain(As, Bs, hbuf, W2T, tbuf, 1024, 1024,
                          (b >> 2) * 256, (b & 3) * 256, s2, o2, 1);
    } else {
        int b2 = b - tBlocks;
        dev_aff(As, Bs, f_g, ps0, po0, sfcT, 1024,
                (b2 & 3) * 128, b2 >> 2, s3, o3, sclW, w_acc);
    }
}

// ---------- gemm256 (R13-verified): pair / batch / fuse paths --------------
__global__ __launch_bounds__(512) void gemm256(
    const bf16* __restrict__ A,
    const float* __restrict__ pairX, const float* __restrict__ pairY,
    const float* __restrict__ ps, const float* __restrict__ po,
    const bf16* __restrict__ BT,
    bf16* __restrict__ C,
    int K, int N, int rowOff,
    long long batchA, long long batchB, long long batchC,
    const float* __restrict__ scale, const float* __restrict__ offset,
    int lrelu,
    const float* __restrict__ fuseW, float* __restrict__ facc,
    long long faccStride)
{
    __shared__ bf16 As[256 * 64];
    __shared__ bf16 Bs[256 * 64];
    const int tid  = threadIdx.x;
    const int lane = tid & 63;
    const int wave = tid >> 6;
    const int wrow = wave >> 2, wcol = wave & 3;
    const int row0 = blockIdx.y * 256;
    const int col0 = blockIdx.x * 256;
    const int q = lane >> 4, l16 = lane & 15;
    const int z = blockIdx.z;

    const bf16* Ap = A + (size_t)z * (size_t)batchA;
    const bf16* Bp = BT + (size_t)z * (size_t)batchB;

    f32x4 acc[8][4];
#pragma unroll
    for (int mi = 0; mi < 8; ++mi)
#pragma unroll
        for (int ni = 0; ni < 4; ++ni)
#pragma unroll
            for (int e = 0; e < 4; ++e) acc[mi][ni][e] = 0.f;

    for (int kk = 0; kk < K; kk += 64) {
        if (pairX) {
#pragma unroll
            for (int t = 0; t < 4; ++t) {
                int c = tid + t * 512;
                int r = c >> 3, ch = c & 7;
                int gr = rowOff + row0 + r;
                const float* xp = pairX + (size_t)(gr >> 8) * K + kk + ch * 8;
                const float* yp = pairY + (size_t)(gr & 255) * K + kk + ch * 8;
                f32x4 x0 = *(const f32x4*)xp, x1 = *(const f32x4*)(xp + 4);
                f32x4 y0 = *(const f32x4*)yp, y1 = *(const f32x4*)(yp + 4);
                f32x4 sa = *(const f32x4*)(ps + kk + ch * 8);
                f32x4 sb = *(const f32x4*)(ps + kk + ch * 8 + 4);
                f32x4 oa = *(const f32x4*)(po + kk + ch * 8);
                f32x4 ob = *(const f32x4*)(po + kk + ch * 8 + 4);
                bf16x8 dv;
#pragma unroll
                for (int j = 0; j < 4; ++j) {
                    float d0 = x0[j] - y0[j];
                    float d1 = x1[j] - y1[j];
                    dv[j]     = (bf16)(d0 * d0 * sa[j] + oa[j]);
                    dv[j + 4] = (bf16)(d1 * d1 * sb[j] + ob[j]);
                }
                *(bf16x8*)&As[r * 64 + ((ch ^ (r & 7)) * 8)] = dv;
            }
        } else {
#pragma unroll
            for (int t = 0; t < 4; ++t) {
                int idx = t * 512 + tid;
                int r = idx >> 3, sch = idx & 7;
                int gch = sch ^ (r & 7);
                async_load16(Ap + (size_t)(row0 + r) * K + kk + gch * 8,
                             &As[idx * 8]);
            }
        }
#pragma unroll
        for (int t = 0; t < 4; ++t) {
            int idx = t * 512 + tid;
            int r = idx >> 3, sch = idx & 7;
            int gch = sch ^ (r & 7);
            async_load16(Bp + (size_t)(col0 + r) * K + kk + gch * 8,
                         &Bs[idx * 8]);
        }
        __syncthreads();

#pragma unroll
        for (int s = 0; s < 2; ++s) {
            bf16x8 af[8], bfr[4];
#pragma unroll
            for (int mi = 0; mi < 8; ++mi) {
                int r = wrow * 128 + mi * 16 + l16;
                af[mi] = *(const bf16x8*)&As[r * 64 + (((s * 4 + q) ^ (r & 7)) * 8)];
            }
#pragma unroll
            for (int ni = 0; ni < 4; ++ni) {
                int rc = wcol * 64 + ni * 16 + l16;
                bfr[ni] = *(const bf16x8*)&Bs[rc * 64 + (((s * 4 + q) ^ (rc & 7)) * 8)];
            }
#pragma unroll
            for (int mi = 0; mi < 8; ++mi)
#pragma unroll
                for (int ni = 0; ni < 4; ++ni)
                    acc[mi][ni] = __builtin_amdgcn_mfma_f32_16x16x32_bf16(
                        af[mi], bfr[ni], acc[mi][ni], 0, 0, 0);
        }
        __syncthreads();
    }

    if (fuseW) {
#pragma unroll
        for (int mi = 0; mi < 8; ++mi)
#pragma unroll
            for (int i = 0; i < 4; ++i) {
                float rs = 0.f;
#pragma unroll
                for (int ni = 0; ni < 4; ++ni) {
                    int cc = col0 + wcol * 64 + ni * 16 + l16;
                    float val = acc[mi][ni][i] * scale[cc] + offset[cc];
                    val = val > 0.f ? val : 0.1f * val;
                    rs += val * fuseW[cc];
                }
                rs += __shfl_xor(rs, 1, 64);
                rs += __shfl_xor(rs, 2, 64);
                rs += __shfl_xor(rs, 4, 64);
                rs += __shfl_xor(rs, 8, 64);
                if (l16 == 0) {
                    int r = row0 + wrow * 128 + mi * 16 + q * 4 + i;
                    atomicAdd(facc + (size_t)z * faccStride + r, rs);
                }
            }
        return;
    }
    bf16* Cp = C + (size_t)z * (size_t)batchC;
#pragma unroll
    for (int mi = 0; mi < 8; ++mi)
#pragma unroll
        for (int ni = 0; ni < 4; ++ni)
#pragma unroll
            for (int i = 0; i < 4; ++i) {
                int r = row0 + wrow * 128 + mi * 16 + q * 4 + i;
                int cc = col0 + wcol * 64 + ni * 16 + l16;
                float val = acc[mi][ni][i];
                if (scale) val = val * scale[cc] + offset[cc];
                if (lrelu) val = val > 0.f ? val : 0.1f * val;
                Cp[(size_t)r * N + cc] = (bf16)val;
            }
}

// standalone affinity (fallback when nc>1)
__global__ __launch_bounds__(512) void gemm_aff(
    const float* __restrict__ pairX,
    const float* __restrict__ ps, const float* __restrict__ po,
    const bf16* __restrict__ BT, int K,
    const float* __restrict__ scale, const float* __restrict__ offset,
    const float* __restrict__ sclW, float* __restrict__ w_acc)
{
    __shared__ bf16 As[256 * 64];
    __shared__ bf16 Bs[128 * 64];
    dev_aff(As, Bs, pairX, ps, po, BT, K,
            blockIdx.x * 128, blockIdx.y, scale, offset, sclW, w_acc);
}

extern "C" void kernel_launch(void* const* d_in, const int* in_sizes, int n_in,
                              void* d_out, int out_size, void* d_ws, size_t ws_size,
                              hipStream_t stream)
{
    const float* f_p   = (const float*)d_in[0];
    const float* f_g   = (const float*)d_in[1];
    const float* bn_g  = (const float*)d_in[2];
    const float* bn_b  = (const float*)d_in[3];
    const float* bn_m  = (const float*)d_in[4];
    const float* bn_v  = (const float*)d_in[5];
    const float* rf_W1 = (const float*)d_in[6];
    const float* rf_b1 = (const float*)d_in[7];
    const float* rf1_g = (const float*)d_in[8];
    const float* rf1_b = (const float*)d_in[9];
    const float* rf1_m = (const float*)d_in[10];
    const float* rf1_v = (const float*)d_in[11];
    const float* rf_W2 = (const float*)d_in[12];
    const float* rf_b2 = (const float*)d_in[13];
    const float* rf2_g = (const float*)d_in[14];
    const float* rf2_b = (const float*)d_in[15];
    const float* rf2_m = (const float*)d_in[16];
    const float* rf2_v = (const float*)d_in[17];
    const float* sfc_W = (const float*)d_in[18];
    const float* sfc_b = (const float*)d_in[19];
    const float* sbn_g = (const float*)d_in[20];
    const float* sbn_b = (const float*)d_in[21];
    const float* sbn_m = (const float*)d_in[22];
    const float* sbn_v = (const float*)d_in[23];
    const float* scl_W = (const float*)d_in[24];
    const float* scl_b = (const float*)d_in[25];
    const float* ffc_W = (const float*)d_in[26];
    const float* ffc_b = (const float*)d_in[27];
    const float* fbn_g = (const float*)d_in[28];
    const float* fbn_b = (const float*)d_in[29];
    const float* fbn_m = (const float*)d_in[30];
    const float* fbn_v = (const float*)d_in[31];
    const float* cls_W = (const float*)d_in[32];
    const float* cls_b = (const float*)d_in[33];

    const size_t MB = 1ull << 20;
    char* ws = (char*)d_ws;
    float* SC      = (float*)(ws);
    float *s0 = SC,        *o0 = SC + 1024;
    float *s1 = SC + 2048, *o1 = SC + 3072;
    float *s2 = SC + 4096, *o2 = SC + 5120;
    float *s3 = SC + 6144, *o3 = SC + 6656;
    float *s4 = SC + 7168, *o4 = SC + 7680;
    float* w_acc   = (float*)(ws + 65536);       // 256 KiB
    float* out_acc = (float*)(ws + 327680);      // 128 KiB
    bf16* wT       = (bf16*)(ws + 458752);       // 128 KiB
    bf16* W1T      = (bf16*)(ws + 1 * MB);
    bf16* W2T      = (bf16*)(ws + 3 * MB);
    bf16* sfcT     = (bf16*)(ws + 5 * MB);
    bf16* ffcT     = (bf16*)(ws + 6 * MB);

    int nc;
    if      (ws_size >= 170 * MB) nc = 1;        // confirmed since R3
    else if (ws_size >= 90 * MB)  nc = 2;
    else                          nc = 4;
    const int pc = 128 / nc;
    const int R  = pc * 256;
    const size_t hbytes = (size_t)R * 1024 * 2;
    bf16* bufA = (bf16*)(ws + 8 * MB);                    // h
    bf16* bufB = (bf16*)(ws + 8 * MB + hbytes);           // t
    bf16* bufC = (bf16*)(ws + 8 * MB + 2 * hbytes);       // uT [pc][512][256]

    // 1. BN folds
    prep_kernel<<<dim3(4), 256, 0, stream>>>(bn_g, bn_b, bn_m, bn_v, nullptr, s0, o0, 1024);
    prep_kernel<<<dim3(4), 256, 0, stream>>>(rf1_g, rf1_b, rf1_m, rf1_v, rf_b1, s1, o1, 1024);
    prep_kernel<<<dim3(4), 256, 0, stream>>>(rf2_g, rf2_b, rf2_m, rf2_v, rf_b2, s2, o2, 1024);
    prep_kernel<<<dim3(2), 256, 0, stream>>>(sbn_g, sbn_b, sbn_m, sbn_v, sfc_b, s3, o3, 512);
    prep_kernel<<<dim3(2), 256, 0, stream>>>(fbn_g, fbn_b, fbn_m, fbn_v, ffc_b, s4, o4, 512);

    // 2. weight transposes (f32 -> bf16)
    wtrans_kernel<<<dim3(4, 1024), 256, 0, stream>>>(rf_W1, W1T, 1024, 1024);
    wtrans_kernel<<<dim3(4, 1024), 256, 0, stream>>>(rf_W2, W2T, 1024, 1024);
    wtrans_kernel<<<dim3(4, 512), 256, 0, stream>>>(sfc_W, sfcT, 1024, 512);
    wtrans_kernel<<<dim3(4, 512), 256, 0, stream>>>(ffc_W, ffcT, 1024, 512);

    // 3. zero accumulators (w_acc + out_acc contiguous)
    hipMemsetAsync(ws + 65536, 0, 393216, stream);

    if (nc == 1) {
        // 4. h = lrelu(rf1(d @ W1 + b1))   [32768,1024] (pair-fused)
        gemm256<<<dim3(4, 128), 512, 0, stream>>>(
            nullptr, f_p, f_g, s0, o0, W1T, bufA, 1024, 1024, 0,
            0, 0, 0, s1, o1, 1, nullptr, nullptr, 0);
        // 5. MERGED: t (512 fat blocks) + symmetric affinity (544 light)
        gemm_taff<<<dim3(512 + 544), 512, 0, stream>>>(
            bufA, W2T, bufB, s2, o2,
            f_g, s0, o0, sfcT, s3, o3, scl_W, w_acc, 512);
        // 6. wT[g2][g1] = bf16(w[canon] + scl_b)
        wconv_kernel<<<dim3(256), 256, 0, stream>>>(w_acc, scl_b, wT);
        // 7. uT_p = ffcT @ t_p^T           [128][512][256]
        gemm256<<<dim3(1, 2, 128), 512, 0, stream>>>(
            ffcT, nullptr, nullptr, nullptr, nullptr, bufB, bufC, 1024, 256, 0,
            0, (long long)256 * 1024, (long long)512 * 256,
            nullptr, nullptr, 0, nullptr, nullptr, 0);
        // 8. feat_p . cls_W -> out_acc (batched fuse)
        gemm256<<<dim3(2, 1, 128), 512, 0, stream>>>(
            wT, nullptr, nullptr, nullptr, nullptr, bufC, nullptr, 256, 512, 0,
            0, (long long)512 * 256, 0,
            s4, o4, 1, cls_W, out_acc, 256);
    } else {
        gemm_aff<<<dim3(4, 136), 512, 0, stream>>>(
            f_g, s0, o0, sfcT, 1024, s3, o3, scl_W, w_acc);
        wconv_kernel<<<dim3(256), 256, 0, stream>>>(w_acc, scl_b, wT);
        for (int ci = 0; ci < nc; ++ci) {
            gemm256<<<dim3(4, R / 256), 512, 0, stream>>>(
                nullptr, f_p, f_g, s0, o0, W1T, bufA, 1024, 1024, ci * R,
                0, 0, 0, s1, o1, 1, nullptr, nullptr, 0);
            gemm256<<<dim3(4, R / 256), 512, 0, stream>>>(
                bufA, nullptr, nullptr, nullptr, nullptr, W2T, bufB, 1024, 1024, 0,
                0, 0, 0, s2, o2, 1, nullptr, nullptr, 0);
            gemm256<<<dim3(1, 2, pc), 512, 0, stream>>>(
                ffcT, nullptr, nullptr, nullptr, nullptr, bufB, bufC, 1024, 256, 0,
                0, (long long)256 * 1024, (long long)512 * 256,
                nullptr, nullptr, 0, nullptr, nullptr, 0);
            gemm256<<<dim3(2, 1, pc), 512, 0, stream>>>(
                wT, nullptr, nullptr, nullptr, nullptr, bufC, nullptr, 256, 512, 0,
                0, (long long)512 * 256, 0,
                s4, o4, 1, cls_W, out_acc + (size_t)ci * pc * 256, 256);
        }
    }
    // 9. d_out = out_acc + cls_b
    finout_kernel<<<dim3(128), 256, 0, stream>>>(out_acc, cls_b, (float*)d_out);
}